// Round 1
// baseline (1141.255 us; speedup 1.0000x reference)
//
#include <hip/hip_runtime.h>
#include <math.h>

#define NN 100000
#define NE 1600000
#define EPSBN 1e-5f

// ---------------- degree / norm ----------------
__global__ __launch_bounds__(256) void deg_init_kernel(float* __restrict__ deg) {
    int i = blockIdx.x * 256 + threadIdx.x;
    if (i < NN) deg[i] = 1.0f;  // self-loop
}

__global__ __launch_bounds__(256) void deg_accum_kernel(const int* __restrict__ dst,
                                                        float* __restrict__ deg) {
    int e = blockIdx.x * 256 + threadIdx.x;
    if (e < NE) atomicAdd(&deg[dst[e]], 1.0f);
}

__global__ __launch_bounds__(256) void dinv_kernel(float* __restrict__ deg) {
    int i = blockIdx.x * 256 + threadIdx.x;
    if (i < NN) deg[i] = rsqrtf(deg[i]);  // deg >= 1 always (self-loops)
}

// ---------------- GEMMs (write hs = dinv*x@W, and init agg with hs for self-loop) ----
// K=128 -> M=64. block 256 = 4 nodes x 64 feats.
__global__ __launch_bounds__(256) void gemm_128_64(const float* __restrict__ x,
                                                   const float* __restrict__ W,
                                                   const float* __restrict__ dinv,
                                                   float* __restrict__ hs,
                                                   float* __restrict__ agg) {
    __shared__ float xs[4][128];
    int tid = threadIdx.x;
    int bn = blockIdx.x * 4;
    for (int idx = tid; idx < 4 * 128; idx += 256) {
        int ln = idx >> 7, k = idx & 127;
        xs[ln][k] = x[(bn + ln) * 128 + k];
    }
    __syncthreads();
    int ln = tid >> 6, f = tid & 63;
    int n = bn + ln;
    float acc = 0.f;
#pragma unroll
    for (int k = 0; k < 128; ++k) acc = fmaf(xs[ln][k], W[k * 64 + f], acc);
    float v = dinv[n] * acc;
    hs[n * 64 + f] = v;
    agg[n * 64 + f] = v;
}

// K=64 -> M=64. block 256 = 4 nodes x 64 feats.
__global__ __launch_bounds__(256) void gemm_64_64(const float* __restrict__ x,
                                                  const float* __restrict__ W,
                                                  const float* __restrict__ dinv,
                                                  float* __restrict__ hs,
                                                  float* __restrict__ agg) {
    __shared__ float xs[4][64];
    int tid = threadIdx.x;
    int bn = blockIdx.x * 4;
    if (tid < 256) {
        int ln = tid >> 6, k = tid & 63;
        xs[ln][k] = x[(bn + ln) * 64 + k];
    }
    __syncthreads();
    int ln = tid >> 6, f = tid & 63;
    int n = bn + ln;
    float acc = 0.f;
#pragma unroll
    for (int k = 0; k < 64; ++k) acc = fmaf(xs[ln][k], W[k * 64 + f], acc);
    float v = dinv[n] * acc;
    hs[n * 64 + f] = v;
    agg[n * 64 + f] = v;
}

// K=64 -> M=16. block 256 = 16 nodes x 16 feats.
__global__ __launch_bounds__(256) void gemm_64_16(const float* __restrict__ x,
                                                  const float* __restrict__ W,
                                                  const float* __restrict__ dinv,
                                                  float* __restrict__ hs,
                                                  float* __restrict__ agg) {
    __shared__ float xs[16][64];
    int tid = threadIdx.x;
    int bn = blockIdx.x * 16;
    for (int idx = tid; idx < 16 * 64; idx += 256) {
        int ln = idx >> 6, k = idx & 63;
        xs[ln][k] = x[(bn + ln) * 64 + k];
    }
    __syncthreads();
    int ln = tid >> 4, f = tid & 15;
    int n = bn + ln;
    float acc = 0.f;
#pragma unroll
    for (int k = 0; k < 64; ++k) acc = fmaf(xs[ln][k], W[k * 16 + f], acc);
    float v = dinv[n] * acc;
    hs[n * 16 + f] = v;
    agg[n * 16 + f] = v;
}

// ---------------- edge aggregation (atomics) ----------------
__global__ __launch_bounds__(256) void edge_agg64(const int* __restrict__ src,
                                                  const int* __restrict__ dst,
                                                  const float* __restrict__ hs,
                                                  float* __restrict__ agg) {
    long long t = (long long)blockIdx.x * 256 + threadIdx.x;
    int e = (int)(t >> 6);
    int f = (int)(t & 63);
    if (e < NE) {
        int s = src[e], d = dst[e];
        atomicAdd(&agg[d * 64 + f], hs[s * 64 + f]);
    }
}

__global__ __launch_bounds__(256) void edge_agg16(const int* __restrict__ src,
                                                  const int* __restrict__ dst,
                                                  const float* __restrict__ hs,
                                                  float* __restrict__ agg) {
    long long t = (long long)blockIdx.x * 256 + threadIdx.x;
    int e = (int)(t >> 4);
    int f = (int)(t & 15);
    if (e < NE) {
        int s = src[e], d = dst[e];
        atomicAdd(&agg[d * 16 + f], hs[s * 16 + f]);
    }
}

// ---------------- epilogues ----------------
__global__ __launch_bounds__(256) void post64_bn_relu(const float* __restrict__ agg,
                                                      const float* __restrict__ dinv,
                                                      const float* __restrict__ b,
                                                      const float* __restrict__ g,
                                                      const float* __restrict__ be,
                                                      const float* __restrict__ m,
                                                      const float* __restrict__ v,
                                                      float* __restrict__ out) {
    int t = blockIdx.x * 256 + threadIdx.x;
    if (t < NN * 64) {
        int i = t >> 6, f = t & 63;
        float h = dinv[i] * agg[t] + b[f];
        h = g[f] * (h - m[f]) * rsqrtf(v[f] + EPSBN) + be[f];
        out[t] = fmaxf(h, 0.f);
    }
}

__global__ __launch_bounds__(256) void post16_sigmoid(const float* __restrict__ agg,
                                                      const float* __restrict__ dinv,
                                                      const float* __restrict__ b,
                                                      float* __restrict__ out) {
    int t = blockIdx.x * 256 + threadIdx.x;
    if (t < NN * 16) {
        int i = t >> 4, f = t & 15;
        float h = dinv[i] * agg[t] + b[f];
        out[t] = 1.0f / (1.0f + expf(-h));
    }
}

extern "C" void kernel_launch(void* const* d_in, const int* in_sizes, int n_in,
                              void* d_out, int out_size, void* d_ws, size_t ws_size,
                              hipStream_t stream) {
    const float* x   = (const float*)d_in[0];
    const int*   ei  = (const int*)d_in[1];   // [2, E]: src = ei, dst = ei + NE
    const float* W1  = (const float*)d_in[2];
    const float* b1  = (const float*)d_in[3];
    const float* W2  = (const float*)d_in[4];
    const float* b2  = (const float*)d_in[5];
    const float* W3  = (const float*)d_in[6];
    const float* b3  = (const float*)d_in[7];
    const float* g1  = (const float*)d_in[8];
    const float* be1 = (const float*)d_in[9];
    const float* m1  = (const float*)d_in[10];
    const float* v1  = (const float*)d_in[11];
    const float* g2  = (const float*)d_in[12];
    const float* be2 = (const float*)d_in[13];
    const float* m2  = (const float*)d_in[14];
    const float* v2  = (const float*)d_in[15];
    float* out = (float*)d_out;

    const int* srcp = ei;
    const int* dstp = ei + NE;

    // workspace layout (floats): dinv[NN] | B hs[NN*64] | C agg[NN*64] | A h[NN*64]
    float* dinv = (float*)d_ws;
    float* B = dinv + NN;
    float* C = B + (size_t)NN * 64;
    float* A = C + (size_t)NN * 64;

    dim3 blk(256);
    int gN   = (NN + 255) / 256;          // 391
    int gE   = (NE + 255) / 256;          // 6250
    int gN4  = NN / 4;                    // 25000 (GEMM 4 nodes/block)
    int gN16 = NN / 16;                   // 6250  (GEMM 16 nodes/block)
    long long e64 = (long long)NE * 64;
    int gE64 = (int)((e64 + 255) / 256);  // 400000
    int gE16 = (int)(((long long)NE * 16 + 255) / 256);  // 100000
    int gP64 = (NN * 64 + 255) / 256;     // 25000
    int gP16 = (NN * 16 + 255) / 256;     // 6250

    // degree / dinv
    deg_init_kernel<<<gN, blk, 0, stream>>>(dinv);
    deg_accum_kernel<<<gE, blk, 0, stream>>>(dstp, dinv);
    dinv_kernel<<<gN, blk, 0, stream>>>(dinv);

    // layer 1: x[N,128] @ W1 -> 64
    gemm_128_64<<<gN4, blk, 0, stream>>>(x, W1, dinv, B, C);
    edge_agg64<<<gE64, blk, 0, stream>>>(srcp, dstp, B, C);
    post64_bn_relu<<<gP64, blk, 0, stream>>>(C, dinv, b1, g1, be1, m1, v1, A);

    // layer 2: A[N,64] @ W2 -> 64
    gemm_64_64<<<gN4, blk, 0, stream>>>(A, W2, dinv, B, C);
    edge_agg64<<<gE64, blk, 0, stream>>>(srcp, dstp, B, C);
    post64_bn_relu<<<gP64, blk, 0, stream>>>(C, dinv, b2, g2, be2, m2, v2, A);

    // layer 3: A[N,64] @ W3 -> 16
    gemm_64_16<<<gN16, blk, 0, stream>>>(A, W3, dinv, B, C);
    edge_agg16<<<gE16, blk, 0, stream>>>(srcp, dstp, B, C);
    post16_sigmoid<<<gP16, blk, 0, stream>>>(C, dinv, b3, out);
}

// Round 2
// 698.790 us; speedup vs baseline: 1.6332x; 1.6332x over previous
//
#include <hip/hip_runtime.h>
#include <math.h>

#define NN 100000
#define NE 1600000
#define EPSBN 1e-5f
#define NB_SCAN 391   // ceil(NN/256)

// ---------------- CSR build ----------------
__global__ __launch_bounds__(256) void zero_cnt(int* __restrict__ cnt) {
    int i = blockIdx.x * 256 + threadIdx.x;
    if (i < NN) cnt[i] = 0;
}

__global__ __launch_bounds__(256) void hist_kernel(const int* __restrict__ dst,
                                                   int* __restrict__ cnt) {
    int e = blockIdx.x * 256 + threadIdx.x;
    if (e < NE) atomicAdd(&cnt[dst[e]], 1);
}

// per-block exclusive scan; write local exclusive + block total
__global__ __launch_bounds__(256) void scan1(const int* __restrict__ cnt,
                                             int* __restrict__ rex,
                                             int* __restrict__ part) {
    __shared__ int sh[256];
    int t = threadIdx.x;
    int i = blockIdx.x * 256 + t;
    int val = (i < NN) ? cnt[i] : 0;
    sh[t] = val;
    __syncthreads();
    for (int off = 1; off < 256; off <<= 1) {
        int x = (t >= off) ? sh[t - off] : 0;
        __syncthreads();
        sh[t] += x;
        __syncthreads();
    }
    if (i < NN) rex[i] = sh[t] - val;
    if (t == 255) part[blockIdx.x] = sh[255];
}

// single block scans the 391 partials (exclusive)
__global__ __launch_bounds__(512) void scan2(const int* __restrict__ part,
                                             int* __restrict__ partoff) {
    __shared__ int sh[512];
    int t = threadIdx.x;
    int val = (t < NB_SCAN) ? part[t] : 0;
    sh[t] = val;
    __syncthreads();
    for (int off = 1; off < 512; off <<= 1) {
        int x = (t >= off) ? sh[t - off] : 0;
        __syncthreads();
        sh[t] += x;
        __syncthreads();
    }
    partoff[t] = sh[t] - val;  // exclusive
}

// finalize row_start, zero cursor, compute dinv = rsqrt(deg+1)
__global__ __launch_bounds__(256) void scan3(const int* __restrict__ rex,
                                             const int* __restrict__ partoff,
                                             const int* __restrict__ cnt,
                                             int* __restrict__ row_start,
                                             int* __restrict__ cursor,
                                             float* __restrict__ dinv) {
    int i = blockIdx.x * 256 + threadIdx.x;
    if (i < NN) {
        row_start[i] = rex[i] + partoff[i >> 8];
        cursor[i] = 0;
        dinv[i] = rsqrtf(1.0f + (float)cnt[i]);
        if (i == 0) row_start[NN] = NE;
    }
}

__global__ __launch_bounds__(256) void scatter_kernel(const int* __restrict__ src,
                                                      const int* __restrict__ dst,
                                                      const int* __restrict__ row_start,
                                                      int* __restrict__ cursor,
                                                      int* __restrict__ sorted_src) {
    int e = blockIdx.x * 256 + threadIdx.x;
    if (e < NE) {
        int d = dst[e];
        int pos = atomicAdd(&cursor[d], 1);
        sorted_src[row_start[d] + pos] = src[e];
    }
}

// ---------------- GEMMs (write hs = dinv * (x@W)) ----------------
__global__ __launch_bounds__(256) void gemm_128_64(const float* __restrict__ x,
                                                   const float* __restrict__ W,
                                                   const float* __restrict__ dinv,
                                                   float* __restrict__ hs) {
    __shared__ float xs[4][128];
    int tid = threadIdx.x;
    int bn = blockIdx.x * 4;
    for (int idx = tid; idx < 4 * 128; idx += 256) {
        int ln = idx >> 7, k = idx & 127;
        xs[ln][k] = x[(bn + ln) * 128 + k];
    }
    __syncthreads();
    int ln = tid >> 6, f = tid & 63;
    int n = bn + ln;
    float acc = 0.f;
#pragma unroll
    for (int k = 0; k < 128; ++k) acc = fmaf(xs[ln][k], W[k * 64 + f], acc);
    hs[n * 64 + f] = dinv[n] * acc;
}

__global__ __launch_bounds__(256) void gemm_64_64(const float* __restrict__ x,
                                                  const float* __restrict__ W,
                                                  const float* __restrict__ dinv,
                                                  float* __restrict__ hs) {
    __shared__ float xs[4][64];
    int tid = threadIdx.x;
    int bn = blockIdx.x * 4;
    {
        int ln = tid >> 6, k = tid & 63;
        xs[ln][k] = x[(bn + ln) * 64 + k];
    }
    __syncthreads();
    int ln = tid >> 6, f = tid & 63;
    int n = bn + ln;
    float acc = 0.f;
#pragma unroll
    for (int k = 0; k < 64; ++k) acc = fmaf(xs[ln][k], W[k * 64 + f], acc);
    hs[n * 64 + f] = dinv[n] * acc;
}

__global__ __launch_bounds__(256) void gemm_64_16(const float* __restrict__ x,
                                                  const float* __restrict__ W,
                                                  const float* __restrict__ dinv,
                                                  float* __restrict__ hs) {
    __shared__ float xs[16][64];
    int tid = threadIdx.x;
    int bn = blockIdx.x * 16;
    for (int idx = tid; idx < 16 * 64; idx += 256) {
        int ln = idx >> 6, k = idx & 63;
        xs[ln][k] = x[(bn + ln) * 64 + k];
    }
    __syncthreads();
    int ln = tid >> 4, f = tid & 15;
    int n = bn + ln;
    float acc = 0.f;
#pragma unroll
    for (int k = 0; k < 64; ++k) acc = fmaf(xs[ln][k], W[k * 16 + f], acc);
    hs[n * 16 + f] = dinv[n] * acc;
}

// ---------------- CSR aggregation, fused epilogue ----------------
// one 64-lane wave per dst row; lane = feature
__global__ __launch_bounds__(256) void csr_agg64_bn_relu(const int* __restrict__ rs,
                                                         const int* __restrict__ ss,
                                                         const float* __restrict__ hs,
                                                         const float* __restrict__ dinv,
                                                         const float* __restrict__ b,
                                                         const float* __restrict__ g,
                                                         const float* __restrict__ be,
                                                         const float* __restrict__ m,
                                                         const float* __restrict__ v,
                                                         float* __restrict__ out) {
    int lane = threadIdx.x & 63;
    int r = blockIdx.x * 4 + (threadIdx.x >> 6);
    int e0 = rs[r], e1 = rs[r + 1];
    float acc = hs[(size_t)r * 64 + lane];  // self loop
    for (int base = e0; base < e1; base += 64) {
        int nb = e1 - base;
        if (nb > 64) nb = 64;
        int sidx = (lane < nb) ? ss[base + lane] : 0;
        for (int j = 0; j < nb; ++j) {
            int s = __shfl(sidx, j);
            acc += hs[(size_t)s * 64 + lane];
        }
    }
    float h = dinv[r] * acc + b[lane];
    h = g[lane] * (h - m[lane]) * rsqrtf(v[lane] + EPSBN) + be[lane];
    out[(size_t)r * 64 + lane] = fmaxf(h, 0.f);
}

// 4 dst rows per wave; 16-lane group per row; fused sigmoid
__global__ __launch_bounds__(256) void csr_agg16_sigmoid(const int* __restrict__ rs,
                                                         const int* __restrict__ ss,
                                                         const float* __restrict__ hs,
                                                         const float* __restrict__ dinv,
                                                         const float* __restrict__ b,
                                                         float* __restrict__ out) {
    int lane = threadIdx.x & 63;
    int wid = blockIdx.x * 4 + (threadIdx.x >> 6);
    int grp = lane >> 4, fl = lane & 15;
    int r = wid * 4 + grp;
    int e0 = rs[r], e1 = rs[r + 1];
    float acc = hs[(size_t)r * 16 + fl];  // self loop
    for (int base = e0; base < e1; base += 16) {
        int nb = e1 - base;
        if (nb > 16) nb = 16;
        int sidx = (fl < nb) ? ss[base + fl] : 0;
        for (int j = 0; j < nb; ++j) {
            int s = __shfl(sidx, grp * 16 + j);
            acc += hs[(size_t)s * 16 + fl];
        }
    }
    float h = dinv[r] * acc + b[fl];
    out[(size_t)r * 16 + fl] = 1.0f / (1.0f + expf(-h));
}

extern "C" void kernel_launch(void* const* d_in, const int* in_sizes, int n_in,
                              void* d_out, int out_size, void* d_ws, size_t ws_size,
                              hipStream_t stream) {
    const float* x   = (const float*)d_in[0];
    const int*   ei  = (const int*)d_in[1];   // [2, E]: src = ei, dst = ei + NE
    const float* W1  = (const float*)d_in[2];
    const float* b1  = (const float*)d_in[3];
    const float* W2  = (const float*)d_in[4];
    const float* b2  = (const float*)d_in[5];
    const float* W3  = (const float*)d_in[6];
    const float* b3  = (const float*)d_in[7];
    const float* g1  = (const float*)d_in[8];
    const float* be1 = (const float*)d_in[9];
    const float* m1  = (const float*)d_in[10];
    const float* v1  = (const float*)d_in[11];
    const float* g2  = (const float*)d_in[12];
    const float* be2 = (const float*)d_in[13];
    const float* m2  = (const float*)d_in[14];
    const float* v2  = (const float*)d_in[15];
    float* out = (float*)d_out;

    const int* srcp = ei;
    const int* dstp = ei + NE;

    // workspace layout
    float* dinv = (float*)d_ws;                    // NN
    float* B    = dinv + NN;                       // NN*64 (hs)
    float* A    = B + (size_t)NN * 64;             // NN*64 (activations)
    int* cnt        = (int*)(A + (size_t)NN * 64); // NN
    int* rex        = cnt + NN;                    // NN
    int* row_start  = rex + NN;                    // NN+1
    int* cursor     = row_start + NN + 2;          // NN
    int* part       = cursor + NN;                 // 512
    int* partoff    = part + 512;                  // 512
    int* sorted_src = partoff + 512;               // NE

    dim3 blk(256);
    int gN   = (NN + 255) / 256;   // 391
    int gE   = (NE + 255) / 256;   // 6250
    int gN4  = NN / 4;             // 25000
    int gN16 = NN / 16;            // 6250
    int gW4  = NN / 4 / 4 + ((NN / 4) % 4 ? 1 : 0);  // blocks for agg16: 25000 waves /4

    // CSR build
    zero_cnt<<<gN, blk, 0, stream>>>(cnt);
    hist_kernel<<<gE, blk, 0, stream>>>(dstp, cnt);
    scan1<<<gN, blk, 0, stream>>>(cnt, rex, part);
    scan2<<<1, 512, 0, stream>>>(part, partoff);
    scan3<<<gN, blk, 0, stream>>>(rex, partoff, cnt, row_start, cursor, dinv);
    scatter_kernel<<<gE, blk, 0, stream>>>(srcp, dstp, row_start, cursor, sorted_src);

    // layer 1
    gemm_128_64<<<gN4, blk, 0, stream>>>(x, W1, dinv, B);
    csr_agg64_bn_relu<<<gN4, blk, 0, stream>>>(row_start, sorted_src, B, dinv,
                                               b1, g1, be1, m1, v1, A);
    // layer 2
    gemm_64_64<<<gN4, blk, 0, stream>>>(A, W2, dinv, B);
    csr_agg64_bn_relu<<<gN4, blk, 0, stream>>>(row_start, sorted_src, B, dinv,
                                               b2, g2, be2, m2, v2, A);
    // layer 3
    gemm_64_16<<<gN16, blk, 0, stream>>>(A, W3, dinv, B);
    csr_agg16_sigmoid<<<gW4, blk, 0, stream>>>(row_start, sorted_src, B, dinv, b3, out);
}